// Round 7
// baseline (598.138 us; speedup 1.0000x reference)
//
#include <hip/hip_runtime.h>
#include <hip/hip_bf16.h>
#include <cstdint>

// DiT block: B=8, N=1024, HID=1024, NH=16, HD=64, MLP=4096.
// R7: gemm_bt K-loop restructured into a pipelined double-buffered form:
// prefetch tile k+1 via global_load_lds into the alternate LDS stage, then
// raw s_barrier + s_waitcnt vmcnt(8) (never 0 mid-loop) so the prefetch
// stays in flight across the MFMA phase (AITER-style; replaces the
// __syncthreads vmcnt(0) full drain that exposed DMA latency every iter).
// Ordering: barrier#1 (prev reads retired by all waves) -> issue DMA(k+1)
// -> vmcnt(8) (own DMA(k) done) -> barrier#2 (all waves' DMA(k) done)
// -> consume. 32x32x16 MFMA inner loop (R6), fused QKV, tanh-GELU,
// MFMA flash attention (R5) unchanged.

typedef __bf16 bf16;
typedef __attribute__((ext_vector_type(8))) __bf16 bf16x8;
typedef __attribute__((ext_vector_type(4))) __bf16 bf16x4;
typedef __attribute__((ext_vector_type(4))) float f32x4;
typedef __attribute__((ext_vector_type(16))) float f32x16;

#define SEQ   1024
#define NHID  1024
#define NHEAD 16
#define HDIM  64
#define CMS   6144          // cmod row stride

// async 16B global->LDS: lds dest = wave-uniform base + lane*16
#define GLD16(gp, lp)                                                  \
  __builtin_amdgcn_global_load_lds(                                    \
      (const __attribute__((address_space(1))) void*)(gp),             \
      (__attribute__((address_space(3))) void*)(lp), 16, 0, 0)

// ---------------------------------------------------------------------------
// Batched transpose + fp32->bf16 convert for four 1024x1024 weights.
// ---------------------------------------------------------------------------
struct TP4 { const float* s[4]; bf16* d[4]; };

__global__ __launch_bounds__(256) void transpose_conv4(TP4 p)
{
  __shared__ float tile[32][33];
  const float* __restrict__ src = p.s[blockIdx.z];
  bf16* __restrict__ dst = p.d[blockIdx.z];
  int n0 = blockIdx.x * 32, k0 = blockIdx.y * 32;
  int tx = threadIdx.x & 31, ty = threadIdx.x >> 5;
#pragma unroll
  for (int i = 0; i < 32; i += 8)
    tile[ty + i][tx] = src[(size_t)(k0 + ty + i) * 1024 + n0 + tx];
  __syncthreads();
#pragma unroll
  for (int i = 0; i < 32; i += 8)
    dst[(size_t)(n0 + ty + i) * 1024 + k0 + tx] = (bf16)tile[tx][ty + i];
}

__global__ __launch_bounds__(256) void transpose_conv(
    const float* __restrict__ src, bf16* __restrict__ dst, int K, int N)
{
  __shared__ float tile[32][33];
  int n0 = blockIdx.x * 32, k0 = blockIdx.y * 32;
  int tx = threadIdx.x & 31, ty = threadIdx.x >> 5;
#pragma unroll
  for (int i = 0; i < 32; i += 8)
    tile[ty + i][tx] = src[(size_t)(k0 + ty + i) * N + n0 + tx];
  __syncthreads();
#pragma unroll
  for (int i = 0; i < 32; i += 8)
    dst[(size_t)(n0 + ty + i) * K + k0 + tx] = (bf16)tile[tx][ty + i];
}

// ---------------------------------------------------------------------------
// cmod = silu(c) @ w_ada + b_ada      c:[8][1024]  w_ada:[1024][6144]
// ---------------------------------------------------------------------------
__global__ __launch_bounds__(256) void ada_kernel(
    const float* __restrict__ c, const float* __restrict__ w_ada,
    const float* __restrict__ b_ada, float* __restrict__ cmod)
{
  __shared__ float cs[1024];
  int b = blockIdx.y;
  int col = blockIdx.x * 256 + threadIdx.x;
  for (int i = threadIdx.x; i < 1024; i += 256) {
    float cv = c[b * 1024 + i];
    cs[i] = cv / (1.0f + __expf(-cv));
  }
  __syncthreads();
  float acc = b_ada[col];
#pragma unroll 8
  for (int kk = 0; kk < 1024; kk++)
    acc += cs[kk] * w_ada[(size_t)kk * CMS + col];
  cmod[b * CMS + col] = acc;
}

// ---------------------------------------------------------------------------
// LayerNorm (no affine) + modulate -> bf16.  One block per row.
// ---------------------------------------------------------------------------
__global__ __launch_bounds__(256) void ln_mod(
    const float* __restrict__ x, const float* __restrict__ cmod,
    bf16* __restrict__ out, int sh_off, int sc_off)
{
  int row = blockIdx.x, b = row >> 10, tid = threadIdx.x;
  const float4* xr = (const float4*)(x + (size_t)row * NHID);
  float4 v = xr[tid];
  float s  = v.x + v.y + v.z + v.w;
  float s2 = v.x * v.x + v.y * v.y + v.z * v.z + v.w * v.w;
#pragma unroll
  for (int off = 32; off; off >>= 1) {
    s  += __shfl_xor(s, off);
    s2 += __shfl_xor(s2, off);
  }
  __shared__ float red1[4], red2[4];
  int wave = tid >> 6, lane = tid & 63;
  if (lane == 0) { red1[wave] = s; red2[wave] = s2; }
  __syncthreads();
  float S  = red1[0] + red1[1] + red1[2] + red1[3];
  float S2 = red2[0] + red2[1] + red2[2] + red2[3];
  float mean = S * (1.0f / NHID);
  float var  = S2 * (1.0f / NHID) - mean * mean;
  float rs   = rsqrtf(var + 1e-6f);
  const float4* shp = (const float4*)(cmod + b * CMS + sh_off);
  const float4* scp = (const float4*)(cmod + b * CMS + sc_off);
  float4 sh4 = shp[tid], sc4 = scp[tid];
  bf16x4 o4;
  o4[0] = (bf16)((v.x - mean) * rs * (1.0f + sc4.x) + sh4.x);
  o4[1] = (bf16)((v.y - mean) * rs * (1.0f + sc4.y) + sh4.y);
  o4[2] = (bf16)((v.z - mean) * rs * (1.0f + sc4.z) + sh4.z);
  o4[3] = (bf16)((v.w - mean) * rs * (1.0f + sc4.w) + sh4.w);
  *(bf16x4*)(out + (size_t)row * NHID + tid * 4) = o4;
}

// ---------------------------------------------------------------------------
// GEMM: C[M][N] = A[M][K](bf16) @ Bt[N][K](bf16)^T + bias, fused epilogues.
// 128x128 tile, BK=64 double-buffered (2x32KB LDS), 4 waves (2x2 of 64x64),
// mfma 32x32x16 bf16 (2x2 of 32x32 per wave). Pipelined K-loop (see header).
// EPI: 1 = fp32 out = resid + gate*val (WO)
//      2 = bf16 tanh-gelu (W1)   3 = fp32 out = resid + gate*val (W2/final)
//      5 = fused QKV: col<1024 -> q, <2048 -> k, else v TRANSPOSED
// ---------------------------------------------------------------------------
template <int EPI>
__global__ __launch_bounds__(256) void gemm_bt(
    const bf16* __restrict__ A, const bf16* __restrict__ Bt,
    const float* __restrict__ bias, const float* __restrict__ bias2,
    const float* __restrict__ bias3,
    bf16* __restrict__ outb, bf16* __restrict__ outb2,
    bf16* __restrict__ outb3, float* __restrict__ outf,
    const float* __restrict__ cmod, int gate_off,
    const float* __restrict__ resid,
    int N, int K)
{
  // [stage][A(0)/B(1)][128*64]
  __shared__ __align__(16) bf16 SM[2][2][128 * 64];
  const int tid = threadIdx.x;
  const int bm = blockIdx.y * 128, bn = blockIdx.x * 128;

  const int wave = tid >> 6, lane = tid & 63;
  const int l32 = lane & 31, half = lane >> 5;
  const int wm = (wave >> 1) * 64, wn = (wave & 1) * 64;

  const int sr = tid >> 3;                 // staging row for i=0
  const int sc = tid & 7;

  f32x16 acc[2][2];
#pragma unroll
  for (int i = 0; i < 2; i++)
#pragma unroll
    for (int j = 0; j < 2; j++) acc[i][j] = (f32x16)0.0f;

  // stage tile kt into stage s: each thread 8 GLD16 (4 per matrix... 4 i x 2)
  auto stage = [&](int kt, int s) {
    int k0 = kt * 64;
#pragma unroll
    for (int i = 0; i < 4; i++) {
      int r = i * 32 + sr;
      int cg = (sc ^ (r & 7)) * 8;
      bf16* la = &SM[s][0][0] + (size_t)(i * 256 + (tid & 192)) * 8;
      bf16* lb = &SM[s][1][0] + (size_t)(i * 256 + (tid & 192)) * 8;
      GLD16(A  + (size_t)(bm + r) * K + k0 + cg, la);
      GLD16(Bt + (size_t)(bn + r) * K + k0 + cg, lb);
    }
  };

  const int NI = K >> 6;
  stage(0, 0);

  for (int kt = 0; kt < NI; kt++) {
    const int cur = kt & 1;
    // barrier #1: all waves' reads of buf[cur^1] (iter kt-1) have retired
    // (fragment loads are consumed by MFMAs before barrier arrival).
    __asm__ volatile("s_barrier" ::: "memory");
    if (kt + 1 < NI) {
      stage(kt + 1, cur ^ 1);                       // 8 GLD16 in flight
      __asm__ volatile("s_waitcnt vmcnt(8)" ::: "memory");  // DMA(kt) done
    } else {
      __asm__ volatile("s_waitcnt vmcnt(0)" ::: "memory");
    }
    // barrier #2: every wave's DMA(kt) complete -> buf[cur] fully visible
    __asm__ volatile("s_barrier" ::: "memory");

    const bf16* As = &SM[cur][0][0];
    const bf16* Bs = &SM[cur][1][0];
#pragma unroll
    for (int kk = 0; kk < 4; kk++) {       // k-step of 16
      int cc = kk * 2 + half;              // chunk col for this lane
      bf16x8 af[2], bfr[2];
#pragma unroll
      for (int t = 0; t < 2; t++) {
        int ra = wm + t * 32 + l32;
        int rb = wn + t * 32 + l32;
        af[t]  = *(const bf16x8*)(As + ra * 64 + ((cc ^ (ra & 7)) * 8));
        bfr[t] = *(const bf16x8*)(Bs + rb * 64 + ((cc ^ (rb & 7)) * 8));
      }
#pragma unroll
      for (int mt = 0; mt < 2; mt++)
#pragma unroll
        for (int nt = 0; nt < 2; nt++)
          acc[mt][nt] = __builtin_amdgcn_mfma_f32_32x32x16_bf16(
              af[mt], bfr[nt], acc[mt][nt], 0, 0, 0);
    }
  }

  // block-uniform epilogue select for EPI==5
  const int sel = bn >> 10;
  const float* bp = (EPI == 5)
      ? ((sel == 0) ? bias : (sel == 1) ? bias2 : bias3) : bias;
  bf16* qk_out = (EPI == 5) ? ((sel == 0) ? outb : outb2) : outb;

#pragma unroll
  for (int mt = 0; mt < 2; mt++) {
#pragma unroll
    for (int nt = 0; nt < 2; nt++) {
      int col = bn + wn + nt * 32 + l32;
      int colq = col & 1023;
      float bcol = (EPI == 5) ? bp[colq] : bias[col];
#pragma unroll
      for (int g = 0; g < 4; g++) {
        int row0 = bm + wm + mt * 32 + g * 8 + half * 4;
        if (EPI == 5 && sel == 2) {
          // V: transposed write vt[b][hid][seq]; 4 consecutive seq rows
          bf16x4 o4;
#pragma unroll
          for (int r = 0; r < 4; r++)
            o4[r] = (bf16)(acc[mt][nt][g * 4 + r] + bcol);
          int bb = row0 >> 10;
          *(bf16x4*)(outb3 + ((size_t)bb * NHID + colq) * SEQ +
                     (row0 & 1023)) = o4;
        } else if (EPI == 5) {
#pragma unroll
          for (int r = 0; r < 4; r++)
            qk_out[(size_t)(row0 + r) * 1024 + colq] =
                (bf16)(acc[mt][nt][g * 4 + r] + bcol);
        } else {
#pragma unroll
          for (int r = 0; r < 4; r++) {
            int row = row0 + r;
            float val = acc[mt][nt][g * 4 + r] + bcol;
            if (EPI == 1 || EPI == 3) {
              int bb = row >> 10;
              float gg = cmod[bb * CMS + gate_off + col];
              outf[(size_t)row * N + col] =
                  resid[(size_t)row * N + col] + gg * val;
            } else {  // EPI == 2: tanh-form GELU
              float u2 = 2.0f * val * (0.7978845608f +
                                       0.0356774081f * val * val);
              float e = __expf(u2);
              float th = 1.0f - 2.0f / (e + 1.0f);
              outb[(size_t)row * N + col] = (bf16)(0.5f * val * (1.0f + th));
            }
          }
        }
      }
    }
  }
}

// ---------------------------------------------------------------------------
// MFMA flash attention (unchanged from R5/R6 — passing).
// ---------------------------------------------------------------------------
__global__ __launch_bounds__(256) void attn_mfma(
    const bf16* __restrict__ q, const bf16* __restrict__ k,
    const bf16* __restrict__ vt, bf16* __restrict__ o)
{
  __shared__ __align__(16) bf16 Ks[64 * 64];
  __shared__ __align__(16) bf16 Vs[64 * 64];
  __shared__ __align__(16) bf16 Ps[4][32 * 72];   // [wave][qloc][key] stride 72

  int bid = blockIdx.x;
  int qt = bid & 7, h = (bid >> 3) & 15, b = bid >> 7;
  int tid = threadIdx.x, wave = tid >> 6, lane = tid & 63;
  int quad = lane >> 4, l16 = lane & 15;
  int qbase = qt * 128 + wave * 32;

  bf16x8 qf[2][2];
  const bf16* qp = q + ((size_t)(b * SEQ + qbase)) * NHID + h * HDIM;
#pragma unroll
  for (int nt = 0; nt < 2; nt++)
#pragma unroll
    for (int kk = 0; kk < 2; kk++) {
      bf16x8 t = *(const bf16x8*)(qp + (size_t)(nt * 16 + l16) * NHID +
                                  kk * 32 + quad * 8);
#pragma unroll
      for (int j = 0; j < 8; j++) t[j] = (bf16)((float)t[j] * 0.015625f);
      qf[nt][kk] = t;
    }

  f32x4 oacc[4][2];
#pragma unroll
  for (int mt = 0; mt < 4; mt++)
#pragma unroll
    for (int nt = 0; nt < 2; nt++) oacc[mt][nt] = (f32x4)0.0f;
  float m_[2] = {-3.0e38f, -3.0e38f}, l_[2] = {0.0f, 0.0f};

  const bf16* kb = k + ((size_t)(b * SEQ)) * NHID + h * HDIM;
  const bf16* vb = vt + ((size_t)(b * NHID + h * HDIM)) * SEQ;

  const int sr0 = tid >> 3, sc0 = tid & 7;

  for (int kt = 0; kt < 16; kt++) {
    __syncthreads();   // prior-iter K/V LDS reads done before restage
#pragma unroll
    for (int i = 0; i < 2; i++) {
      int r = i * 32 + sr0;
      int cg = (sc0 ^ (r & 7)) * 8;
      bf16* lk = Ks + (size_t)(i * 256 + (tid & 192)) * 8;
      bf16* lv = Vs + (size_t)(i * 256 + (tid & 192)) * 8;
      GLD16(kb + (size_t)(kt * 64 + r) * NHID + cg, lk);
      GLD16(vb + (size_t)r * SEQ + kt * 64 + cg, lv);
    }
    __syncthreads();

    // ---- S^T = K @ Q^T  (already scaled via qf)
    f32x4 sacc[4][2];
#pragma unroll
    for (int mt = 0; mt < 4; mt++)
#pragma unroll
      for (int nt = 0; nt < 2; nt++) sacc[mt][nt] = (f32x4)0.0f;
#pragma unroll
    for (int kk = 0; kk < 2; kk++) {
      bf16x8 kf[4];
#pragma unroll
      for (int mt = 0; mt < 4; mt++) {
        int row = mt * 16 + l16;
        kf[mt] = *(const bf16x8*)(Ks + row * 64 +
                                  (((kk * 4 + quad) ^ (row & 7)) * 8));
      }
#pragma unroll
      for (int mt = 0; mt < 4; mt++)
#pragma unroll
        for (int nt = 0; nt < 2; nt++)
          sacc[mt][nt] = __builtin_amdgcn_mfma_f32_16x16x32_bf16(
              kf[mt], qf[nt][kk], sacc[mt][nt], 0, 0, 0);
    }

    // ---- online softmax (per q column = per (nt, l16))
    float alpha[2];
#pragma unroll
    for (int nt = 0; nt < 2; nt++) {
      float tm = -3.0e38f;
#pragma unroll
      for (int mt = 0; mt < 4; mt++)
#pragma unroll
        for (int r = 0; r < 4; r++) tm = fmaxf(tm, sacc[mt][nt][r]);
      tm = fmaxf(tm, __shfl_xor(tm, 16));
      tm = fmaxf(tm, __shfl_xor(tm, 32));
      float mn = fmaxf(m_[nt], tm);
      alpha[nt] = __expf(m_[nt] - mn);
      m_[nt] = mn;
      float ts = 0.0f;
#pragma unroll
      for (int mt = 0; mt < 4; mt++) {
        bf16x4 pv;
#pragma unroll
        for (int r = 0; r < 4; r++) {
          float p = __expf(sacc[mt][nt][r] - mn);
          ts += p;
          pv[r] = (bf16)p;
        }
        *(bf16x4*)(&Ps[wave][(nt * 16 + l16) * 72 + mt * 16 + quad * 4]) = pv;
      }
      ts += __shfl_xor(ts, 16);
      ts += __shfl_xor(ts, 32);
      l_[nt] = l_[nt] * alpha[nt] + ts;
    }
#pragma unroll
    for (int mt = 0; mt < 4; mt++)
#pragma unroll
      for (int nt = 0; nt < 2; nt++)
#pragma unroll
        for (int r = 0; r < 4; r++) oacc[mt][nt][r] *= alpha[nt];

    // Wave-level fence: Ps is wave-private (R2/R5 post-mortems).
    __asm__ volatile("s_waitcnt lgkmcnt(0)" ::: "memory");

    // ---- O^T += V^T @ P^T
#pragma unroll
    for (int kk = 0; kk < 2; kk++) {
      bf16x8 vf[4], pf[2];
#pragma unroll
      for (int mt = 0; mt < 4; mt++) {
        int row = mt * 16 + l16;
        vf[mt] = *(const bf16x8*)(Vs + row * 64 +
                                  (((kk * 4 + quad) ^ (row & 7)) * 8));
      }
#pragma unroll
      for (int nt = 0; nt < 2; nt++)
        pf[nt] = *(const bf16x8*)(&Ps[wave][(nt * 16 + l16) * 72 +
                                            kk * 32 + quad * 8]);
#pragma unroll
      for (int mt = 0; mt < 4; mt++)
#pragma unroll
        for (int nt = 0; nt < 2; nt++)
          oacc[mt][nt] = __builtin_amdgcn_mfma_f32_16x16x32_bf16(
              vf[mt], pf[nt], oacc[mt][nt], 0, 0, 0);
    }
  }

  // ---- write O (un-transposing: per lane 4 consecutive hid cols)
#pragma unroll
  for (int nt = 0; nt < 2; nt++) {
    float rl = 1.0f / l_[nt];
#pragma unroll
    for (int mt = 0; mt < 4; mt++) {
      bf16x4 o4;
#pragma unroll
      for (int r = 0; r < 4; r++) o4[r] = (bf16)(oacc[mt][nt][r] * rl);
      *(bf16x4*)(o + ((size_t)(b * SEQ + qbase + nt * 16 + l16)) * NHID +
                 h * HDIM + mt * 16 + quad * 4) = o4;
    }
  }
}

// ---------------------------------------------------------------------------
// Workspace layout (bytes). Total ~136.2 MiB.
// wqT/wkT/wvT contiguous -> one [3072][1024] QKV weight matrix.
// ---------------------------------------------------------------------------
#define OFF_CMOD 0u
#define OFF_WQT  196608u
#define OFF_WKT  (OFF_WQT + 2097152u)
#define OFF_WVT  (OFF_WKT + 2097152u)
#define OFF_WOT  (OFF_WVT + 2097152u)
#define OFF_W1T  (OFF_WOT + 2097152u)
#define OFF_W2T  (OFF_W1T + 8388608u)
#define OFF_X2   (OFF_W2T + 8388608u)
#define OFF_XM2  (OFF_X2  + 33554432u)
#define OFF_POOL (OFF_XM2 + 16777216u)
// pool (67.1 MB): xm @ +0, q @ +16M, k @ +32M, vt @ +48M.
// o aliases xm (dead after QKV GEMM); h aliases whole pool.

extern "C" void kernel_launch(void* const* d_in, const int* in_sizes, int n_in,
                              void* d_out, int out_size, void* d_ws, size_t ws_size,
                              hipStream_t stream)
{
  const float* x     = (const float*)d_in[0];
  const float* c     = (const float*)d_in[1];
  const float* w_ada = (const float*)d_in[2];
  const float* b_ada = (const float*)d_in[3];
  const float* wq = (const float*)d_in[4];  const float* bq = (const float*)d_in[5];
  const float* wk = (const float*)d_in[6];  const float* bk = (const float*)d_in[7];
  const float* wv = (const float*)d_in[8];  const float* bv = (const float*)d_in[9];
  const float* wo = (const float*)d_in[10]; const float* bo = (const float*)d_in[11];
  const float* w1 = (const float*)d_in[12]; const float* b1 = (const float*)d_in[13];
  const float* w2 = (const float*)d_in[14]; const float* b2 = (const float*)d_in[15];
  float* out = (float*)d_out;
  char* ws = (char*)d_ws;

  float* cmod = (float*)(ws + OFF_CMOD);
  bf16* wqT = (bf16*)(ws + OFF_WQT);     // base of contiguous [3072][1024]
  bf16* wkT = (bf16*)(ws + OFF_WKT);
  bf16* wvT = (bf16*)(ws + OFF_WVT);
  bf16* woT = (bf16*)(ws + OFF_WOT);
  bf16* w1T = (bf16*)(ws + OFF_W1T);
  bf16* w2T = (bf16*)(ws + OFF_W2T);
  float* x2 = (float*)(ws + OFF_X2);
  bf16* xm2 = (bf16*)(ws + OFF_XM2);
  bf16* xm  = (bf16*)(ws + OFF_POOL);
  bf16* qb  = (bf16*)(ws + OFF_POOL + 16777216u);
  bf16* kb  = (bf16*)(ws + OFF_POOL + 33554432u);
  bf16* vtb = (bf16*)(ws + OFF_POOL + 50331648u);
  bf16* ob  = xm;   // alias
  bf16* hb  = xm;   // alias (covers 64 MB of pool)

  TP4 tp;
  tp.s[0] = wq; tp.s[1] = wk; tp.s[2] = wv; tp.s[3] = wo;
  tp.d[0] = wqT; tp.d[1] = wkT; tp.d[2] = wvT; tp.d[3] = woT;
  transpose_conv4<<<dim3(32, 32, 4), 256, 0, stream>>>(tp);
  transpose_conv<<<dim3(128, 32), 256, 0, stream>>>(w1, w1T, 1024, 4096);
  transpose_conv<<<dim3(32, 128), 256, 0, stream>>>(w2, w2T, 4096, 1024);

  ada_kernel<<<dim3(24, 8), 256, 0, stream>>>(c, w_ada, b_ada, cmod);

  // ln1 + modulate (sh_msa @ 0, sc_msa @ 1024)
  ln_mod<<<8192, 256, 0, stream>>>(x, cmod, xm, 0, 1024);

  // fused QKV: N=3072; q/k normal, v transposed (vt[b][hid][seq])
  gemm_bt<5><<<dim3(24, 64), 256, 0, stream>>>(
      xm, wqT, bq, bk, bv, qb, kb, vtb, nullptr, nullptr, 0, nullptr,
      1024, 1024);

  attn_mfma<<<1024, 256, 0, stream>>>(qb, kb, vtb, ob);

  // x2 = x + g_msa * (o @ wo + bo)      (g_msa @ 2048)
  gemm_bt<1><<<dim3(8, 64), 256, 0, stream>>>(
      ob, woT, bo, nullptr, nullptr, nullptr, nullptr, nullptr, x2,
      cmod, 2048, x, 1024, 1024);

  // ln2 + modulate (sh_mlp @ 3072, sc_mlp @ 4096)
  ln_mod<<<8192, 256, 0, stream>>>(x2, cmod, xm2, 3072, 4096);

  // h = gelu(xm2 @ w1 + b1)   (tanh form)
  gemm_bt<2><<<dim3(32, 64), 256, 0, stream>>>(
      xm2, w1T, b1, nullptr, nullptr, hb, nullptr, nullptr, nullptr,
      nullptr, 0, nullptr, 4096, 1024);

  // out = x2 + g_mlp * (h @ w2 + b2)    (g_mlp @ 5120)
  gemm_bt<3><<<dim3(8, 64), 256, 0, stream>>>(
      hb, w2T, b2, nullptr, nullptr, nullptr, nullptr, nullptr, out,
      cmod, 5120, x2, 1024, 4096);
}